// Round 7
// baseline (2743.689 us; speedup 1.0000x reference)
//
#include <hip/hip_runtime.h>
#include <cmath>

#define NN 100000
#define NE 3200000
#define C 128
#define NLAYERS 8
#define PSTRIDE 96   // padded CSR row stride; Poisson(32) max-degree +11 sigma
#define ZSTR 136     // LDS z row stride in u16 (272B: 16B-aligned, bank-padded)

typedef unsigned int u32;
typedef unsigned short u16;
typedef __attribute__((ext_vector_type(8))) short s16x8;
typedef __attribute__((ext_vector_type(4))) float f32x4;

__device__ __forceinline__ float bf2f(u16 u) { return __uint_as_float(((u32)u) << 16); }
__device__ __forceinline__ u16 f2bf(float f) {
    u32 x = __float_as_uint(f);
    return (u16)((x + 0x7fffu + ((x >> 16) & 1u)) >> 16);  // RNE
}

// ---------------- setup kernels ----------------

__global__ void zero_kernel(int* __restrict__ p, int n) {
    int i = blockIdx.x * blockDim.x + threadIdx.x;
    if (i < n) p[i] = 0;
}

// Single pass: atomic on cnt IS degree count AND slot allocator. 1 edge/thread.
__global__ void scatter_kernel(const int* __restrict__ row, const int* __restrict__ col,
                               int* __restrict__ cnt, int* __restrict__ csr, int n) {
    int e = blockIdx.x * blockDim.x + threadIdx.x;
    if (e < n) {
        int d = col[e];
        int slot = atomicAdd(&cnt[d], 1);
        csr[(size_t)d * PSTRIDE + slot] = row[e];
    }
}

__global__ void dinv_kernel(const int* __restrict__ cnt, float* __restrict__ dinv, int n) {
    int i = blockIdx.x * blockDim.x + threadIdx.x;
    if (i < n) dinv[i] = rsqrtf((float)(cnt[i] + 1));  // +1 self loop
}

// Weights -> bf16 hi/lo, B-fragment layout Wb[mat][n*128+k].
// mat 0: proj W as-is. mats 1..8: W' = beta*W + (1-beta)*I  (epilogue folded in)
__global__ void prep_w(const float* __restrict__ Wp, const float* __restrict__ cw,
                       u16* __restrict__ Wbh, u16* __restrict__ Wbl) {
    int tid = blockIdx.x * blockDim.x + threadIdx.x;
    if (tid >= 9 * C * C) return;
    int mat = tid >> 14;
    int r = tid & 16383;
    int n = r >> 7, k = r & 127;  // k fastest -> coalesced writes
    float v;
    if (mat == 0) {
        v = Wp[k * C + n];
    } else {
        float beta = logf(0.5f / (float)mat + 1.0f);
        v = beta * cw[(size_t)(mat - 1) * C * C + k * C + n];
        if (k == n) v += 1.0f - beta;
    }
    u16 hi = f2bf(v);
    float lo = v - bf2f(hi);
    Wbh[tid] = hi;
    Wbl[tid] = f2bf(lo);
}

// ---------------- fused layer: agg (to LDS) + GEMM + epilogue ----------------
// block = 64 nodes, 4 waves. Phase 1: wave w aggregates nodes [w*16, w*16+16),
// z -> LDS hi/lo. Phase 2: 64x128 GEMM, A from LDS, B = W' (beta-folded);
// epilogue hn = acc + h32, relu, write h32/out and g_out = dinv*hn (bf16).

__global__ __launch_bounds__(256) void layer_fused(
    const u16* __restrict__ gin, const u16* __restrict__ x0bf,
    const int* __restrict__ cnt, const int* __restrict__ csr,
    const float* __restrict__ dinv,
    const u16* __restrict__ Wbh, const u16* __restrict__ Wbl,
    const float* __restrict__ h32, float* __restrict__ out32,
    u16* __restrict__ gout, int relu) {
    __shared__ u16 zh[64 * ZSTR];
    __shared__ u16 zl[64 * ZSTR];
    int tid = threadIdx.x;
    int wave = tid >> 6, lane = tid & 63;
    int rowbase = blockIdx.x * 64;
    const u16* gb = gin + (lane << 1);

    // ---- phase 1: aggregation ----
    for (int t = 0; t < 16; ++t) {
        int nl = wave * 16 + t;
        int node = rowbase + nl;
        if (node >= NN) node = NN - 1;
        int deg = __builtin_amdgcn_readfirstlane(cnt[node]);
        const int* cp = csr + (size_t)node * PSTRIDE;
        u32 su = *(const u32*)(gb + (size_t)node * C);  // self-loop term
        float a0 = bf2f((u16)su), a1 = bf2f((u16)(su >> 16));
        float b0 = 0.f, b1 = 0.f, c0 = 0.f, c1 = 0.f, d0 = 0.f, d1 = 0.f;
        int j = 0;
        int nfull = deg & ~7;
        if (j < nfull) {
            int4 ca = *(const int4*)(cp + j);
            int4 cb = *(const int4*)(cp + j + 4);
            while (true) {
                u32 u0 = *(const u32*)(gb + (size_t)(u32)ca.x * C);
                u32 u1 = *(const u32*)(gb + (size_t)(u32)ca.y * C);
                u32 u2 = *(const u32*)(gb + (size_t)(u32)ca.z * C);
                u32 u3 = *(const u32*)(gb + (size_t)(u32)ca.w * C);
                u32 u4 = *(const u32*)(gb + (size_t)(u32)cb.x * C);
                u32 u5 = *(const u32*)(gb + (size_t)(u32)cb.y * C);
                u32 u6 = *(const u32*)(gb + (size_t)(u32)cb.z * C);
                u32 u7 = *(const u32*)(gb + (size_t)(u32)cb.w * C);
                j += 8;
                bool more = j < nfull;
                int4 na, nb;
                if (more) {
                    na = *(const int4*)(cp + j);
                    nb = *(const int4*)(cp + j + 4);
                }
                a0 += bf2f((u16)u0); a1 += bf2f((u16)(u0 >> 16));
                b0 += bf2f((u16)u1); b1 += bf2f((u16)(u1 >> 16));
                c0 += bf2f((u16)u2); c1 += bf2f((u16)(u2 >> 16));
                d0 += bf2f((u16)u3); d1 += bf2f((u16)(u3 >> 16));
                a0 += bf2f((u16)u4); a1 += bf2f((u16)(u4 >> 16));
                b0 += bf2f((u16)u5); b1 += bf2f((u16)(u5 >> 16));
                c0 += bf2f((u16)u6); c1 += bf2f((u16)(u6 >> 16));
                d0 += bf2f((u16)u7); d1 += bf2f((u16)(u7 >> 16));
                if (!more) break;
                ca = na; cb = nb;
            }
        }
        for (; j < deg; ++j) {
            u32 u = *(const u32*)(gb + (size_t)(u32)cp[j] * C);
            a0 += bf2f((u16)u); a1 += bf2f((u16)(u >> 16));
        }
        a0 += (b0 + c0) + d0;
        a1 += (b1 + c1) + d1;
        float dv = dinv[node];
        u32 xu = *(const u32*)(x0bf + (size_t)node * C + (lane << 1));
        float z0 = 0.9f * dv * a0 + 0.1f * bf2f((u16)xu);
        float z1 = 0.9f * dv * a1 + 0.1f * bf2f((u16)(xu >> 16));
        u16 h0 = f2bf(z0), h1 = f2bf(z1);
        u16 l0 = f2bf(z0 - bf2f(h0)), l1 = f2bf(z1 - bf2f(h1));
        *(u32*)(zh + nl * ZSTR + (lane << 1)) = (u32)h0 | ((u32)h1 << 16);
        *(u32*)(zl + nl * ZSTR + (lane << 1)) = (u32)l0 | ((u32)l1 << 16);
    }
    __syncthreads();

    // ---- phase 2: GEMM (z @ W') + epilogue ----
    int quad = lane >> 4, l16 = lane & 15;
    int strip = wave * 16;
    s16x8 ahi[4], alo[4];
#pragma unroll
    for (int c2 = 0; c2 < 4; ++c2) {
        int aoff = (strip + l16) * ZSTR + c2 * 32 + quad * 8;
        ahi[c2] = *(const s16x8*)(zh + aoff);
        alo[c2] = *(const s16x8*)(zl + aoff);
    }
    f32x4 acc[8];
#pragma unroll
    for (int t = 0; t < 8; ++t) acc[t] = f32x4{0.f, 0.f, 0.f, 0.f};
#pragma unroll
    for (int c2 = 0; c2 < 4; ++c2) {
#pragma unroll
        for (int t = 0; t < 8; ++t) {
            int widx = (t * 16 + l16) * C + c2 * 32 + quad * 8;
            s16x8 bh = *(const s16x8*)(Wbh + widx);
            s16x8 bl = *(const s16x8*)(Wbl + widx);
            acc[t] = __builtin_amdgcn_mfma_f32_16x16x32_bf16(ahi[c2], bh, acc[t], 0, 0, 0);
            acc[t] = __builtin_amdgcn_mfma_f32_16x16x32_bf16(alo[c2], bh, acc[t], 0, 0, 0);
            acc[t] = __builtin_amdgcn_mfma_f32_16x16x32_bf16(ahi[c2], bl, acc[t], 0, 0, 0);
        }
    }
    float dv[4];
#pragma unroll
    for (int r = 0; r < 4; ++r) {
        int m = rowbase + strip + quad * 4 + r;
        dv[r] = (m < NN) ? dinv[m] : 0.f;
    }
#pragma unroll
    for (int t = 0; t < 8; ++t) {
        int n = t * 16 + l16;
#pragma unroll
        for (int r = 0; r < 4; ++r) {
            int m = rowbase + strip + quad * 4 + r;
            if (m < NN) {
                size_t idx = (size_t)m * C + n;
                float hn = acc[t][r] + h32[idx];
                if (relu) hn = fmaxf(hn, 0.f);
                out32[idx] = hn;
                gout[idx] = f2bf(dv[r] * hn);
            }
        }
    }
}

// ---------------- projection GEMM (fp32 X -> x0, h32, g) ----------------

__device__ __forceinline__ void build_a(const float* __restrict__ p, s16x8& hi, s16x8& lo) {
#pragma unroll
    for (int j = 0; j < 8; ++j) {
        float v = p[j];
        u16 h = f2bf(v);
        hi[j] = (short)h;
        lo[j] = (short)f2bf(v - bf2f(h));
    }
}

__global__ __launch_bounds__(256) void gemm_proj(
    const float* __restrict__ X, const u16* __restrict__ Wbh, const u16* __restrict__ Wbl,
    const float* __restrict__ bias, const float* __restrict__ dinv,
    u16* __restrict__ x0bf, float* __restrict__ h32, u16* __restrict__ gbf) {
    int tid = threadIdx.x;
    int wave = tid >> 6, lane = tid & 63;
    int quad = lane >> 4, l16 = lane & 15;
    int rowbase = blockIdx.x * 64 + wave * 16;
    int arow = rowbase + l16;
    if (arow >= NN) arow = NN - 1;
    const float* aptr = X + (size_t)arow * C + quad * 8;
    s16x8 ahi[4], alo[4];
#pragma unroll
    for (int c2 = 0; c2 < 4; ++c2) build_a(aptr + c2 * 32, ahi[c2], alo[c2]);
    f32x4 acc[8];
#pragma unroll
    for (int t = 0; t < 8; ++t) acc[t] = f32x4{0.f, 0.f, 0.f, 0.f};
#pragma unroll
    for (int c2 = 0; c2 < 4; ++c2) {
#pragma unroll
        for (int t = 0; t < 8; ++t) {
            int widx = (t * 16 + l16) * C + c2 * 32 + quad * 8;
            s16x8 bh = *(const s16x8*)(Wbh + widx);
            s16x8 bl = *(const s16x8*)(Wbl + widx);
            acc[t] = __builtin_amdgcn_mfma_f32_16x16x32_bf16(ahi[c2], bh, acc[t], 0, 0, 0);
            acc[t] = __builtin_amdgcn_mfma_f32_16x16x32_bf16(alo[c2], bh, acc[t], 0, 0, 0);
            acc[t] = __builtin_amdgcn_mfma_f32_16x16x32_bf16(ahi[c2], bl, acc[t], 0, 0, 0);
        }
    }
    float dv[4];
#pragma unroll
    for (int r = 0; r < 4; ++r) {
        int m = rowbase + quad * 4 + r;
        dv[r] = (m < NN) ? dinv[m] : 0.f;
    }
#pragma unroll
    for (int t = 0; t < 8; ++t) {
        int n = t * 16 + l16;
        float bv = bias[n];
#pragma unroll
        for (int r = 0; r < 4; ++r) {
            int m = rowbase + quad * 4 + r;
            if (m < NN) {
                float v = acc[t][r] + bv;
                size_t idx = (size_t)m * C + n;
                h32[idx] = v;
                x0bf[idx] = f2bf(v);
                gbf[idx] = f2bf(dv[r] * v);
            }
        }
    }
}

// ---------------- host ----------------

extern "C" void kernel_launch(void* const* d_in, const int* in_sizes, int n_in,
                              void* d_out, int out_size, void* d_ws, size_t ws_size,
                              hipStream_t stream) {
    const float* x = (const float*)d_in[0];
    const int* ei = (const int*)d_in[1];
    const float* Wp = (const float*)d_in[2];
    const float* bp = (const float*)d_in[3];
    const float* cw = (const float*)d_in[4];
    const int* row = ei;
    const int* col = ei + NE;

    char* ws = (char*)d_ws;
    size_t o = 0;
    auto alloc = [&](size_t bytes) {
        void* p = ws + o;
        o += (bytes + 255) & ~(size_t)255;
        return p;
    };
    int* cnt = (int*)alloc(NN * 4);
    float* dinv = (float*)alloc(NN * 4);
    int* csr = (int*)alloc((size_t)NN * PSTRIDE * 4);
    u16* x0bf = (u16*)alloc((size_t)NN * C * 2);
    u16* gA = (u16*)alloc((size_t)NN * C * 2);
    u16* gB = (u16*)alloc((size_t)NN * C * 2);
    float* h32 = (float*)alloc((size_t)NN * C * 4);
    u16* Wbh = (u16*)alloc((size_t)9 * C * C * 2);
    u16* Wbl = (u16*)alloc((size_t)9 * C * C * 2);

    zero_kernel<<<(NN + 255) / 256, 256, 0, stream>>>(cnt, NN);
    scatter_kernel<<<(NE + 255) / 256, 256, 0, stream>>>(row, col, cnt, csr, NE);
    dinv_kernel<<<(NN + 255) / 256, 256, 0, stream>>>(cnt, dinv, NN);
    prep_w<<<(9 * C * C + 255) / 256, 256, 0, stream>>>(Wp, cw, Wbh, Wbl);
    gemm_proj<<<(NN + 63) / 64, 256, 0, stream>>>(x, Wbh, Wbl, bp, dinv, x0bf, h32, gA);

    u16* gin = gA;
    u16* gout = gB;
    for (int l = 0; l < NLAYERS; ++l) {
        float* out32 = (l == NLAYERS - 1) ? (float*)d_out : h32;
        layer_fused<<<(NN + 63) / 64, 256, 0, stream>>>(
            gin, x0bf, cnt, csr, dinv,
            Wbh + (size_t)(l + 1) * C * C, Wbl + (size_t)(l + 1) * C * C,
            h32, out32, gout, (l < NLAYERS - 1) ? 1 : 0);
        u16* tmp = gin; gin = gout; gout = tmp;
    }
}